// Round 5
// baseline (47.820 us; speedup 1.0000x reference)
//
#include <hip/hip_runtime.h>
#include <math.h>

// QConv2d: new_rho = kron(Ux,Uy) @ rho @ kron(Ux,Uy)^T
// Ux,Uy 32x32 block-diagonal with four IDENTICAL 8x8 orthogonal blocks.
// Four independent length-8 contractions on axes (x1,y1,x2,y2).
//
// Block = (b,bx1,by1,bx2) = 64 rows x 256 contiguous cols, 256 threads.
// STREAMING form: for each x-group k: load 8 rows -> y-contract -> rank-1
// accumulate with UX[:,k]. 8-load groups feed FMAs immediately -> load
// latency overlaps compute (needs ~90 VGPR; launch_bounds allows 128).
// Transpose via 32KB [32][256] swizzled LDS in two half-passes (waves 0,1
// consume rows 0..31; waves 2,3 rows 32..63). Direct float4 stores.

__global__ void setup_uf(const float* __restrict__ phi_x,
                         const float* __restrict__ phi_y,
                         float* __restrict__ ws) {
    const int t = threadIdx.x;
    if (t < 2) {
        const float* phi = (t == 0) ? phi_x : phi_y;
        float U[8][8];
#pragma unroll
        for (int i = 0; i < 8; ++i)
#pragma unroll
            for (int j = 0; j < 8; ++j) U[i][j] = (i == j) ? 1.0f : 0.0f;
        int idx = 0;
#pragma unroll
        for (int i = 1; i < 8; ++i) {
#pragma unroll
            for (int j = i; j >= 1; --j) {
                const float c = cosf(phi[idx]);
                const float s = sinf(phi[idx]);
#pragma unroll
                for (int m = 0; m < 8; ++m) {
                    const float a = U[j - 1][m], b = U[j][m];
                    U[j - 1][m] = c * a + s * b;
                    U[j][m]     = -s * a + c * b;
                }
                ++idx;
            }
        }
        float* o = ws + t * 64;
#pragma unroll
        for (int i = 0; i < 8; ++i)
#pragma unroll
            for (int j = 0; j < 8; ++j) o[i * 8 + j] = U[i][j];
    }
}

// y-contract raw[8] with UY, then accumulate UX[:,k] (x) w[] into acc[64].
#define STREAM_GROUP(K, RAW, ACC, UXP, UYP)                                    \
    {                                                                          \
        float w_[8];                                                           \
        _Pragma("unroll")                                                      \
        for (int jj = 0; jj < 8; ++jj) {                                       \
            float a_ = 0.0f;                                                   \
            _Pragma("unroll")                                                  \
            for (int j = 0; j < 8; ++j)                                        \
                a_ = fmaf((UYP)[jj * 8 + j], (RAW)[j], a_);                    \
            w_[jj] = a_;                                                       \
        }                                                                      \
        _Pragma("unroll")                                                      \
        for (int i = 0; i < 8; ++i) {                                          \
            const float ux_ = (UXP)[i * 8 + (K)];                              \
            _Pragma("unroll")                                                  \
            for (int jj = 0; jj < 8; ++jj) {                                   \
                if ((K) == 0)                                                  \
                    (ACC)[i * 8 + jj] = ux_ * w_[jj];                          \
                else                                                           \
                    (ACC)[i * 8 + jj] =                                        \
                        fmaf(ux_, w_[jj], (ACC)[i * 8 + jj]);                  \
            }                                                                  \
        }                                                                      \
    }

// Column (y2,x2) transform + direct store for one (rr, by2) unit.
// S holds 32 swizzled rows (base row rr & ~31).
__device__ __forceinline__ void col_phase(const float* __restrict__ S,
                                          const float* __restrict__ UX,
                                          const float* __restrict__ UY,
                                          float* __restrict__ out,
                                          size_t B0, int rowbase, int bx2,
                                          int rr, int by2) {
    const int r2 = rr & 31;
    const int r7 = r2 & 7;
    const float* __restrict__ Srow = S + r2 * 256;

    float q[64];
#pragma unroll
    for (int k = 0; k < 8; ++k) {
        const int c0 = (((k * 8 + by2 * 2 + 0) ^ r7) << 2);
        const int c1 = (((k * 8 + by2 * 2 + 1) ^ r7) << 2);
        const float4 q0 = *reinterpret_cast<const float4*>(&Srow[c0]);
        const float4 q1 = *reinterpret_cast<const float4*>(&Srow[c1]);
        float raw[8];
        raw[0] = q0.x; raw[1] = q0.y; raw[2] = q0.z; raw[3] = q0.w;
        raw[4] = q1.x; raw[5] = q1.y; raw[6] = q1.z; raw[7] = q1.w;
        STREAM_GROUP(k, raw, q, UX, UY)
    }

    const int gr = rowbase + ((rr >> 3) * 32) + (rr & 7);
    float* __restrict__ dst = out + B0 + (size_t)gr * 1024 + bx2 * 256 + by2 * 8;
#pragma unroll
    for (int i = 0; i < 8; ++i) {
        *reinterpret_cast<float4*>(dst + i * 32) =
            make_float4(q[i * 8 + 0], q[i * 8 + 1], q[i * 8 + 2], q[i * 8 + 3]);
        *reinterpret_cast<float4*>(dst + i * 32 + 4) =
            make_float4(q[i * 8 + 4], q[i * 8 + 5], q[i * 8 + 6], q[i * 8 + 7]);
    }
}

__global__ __launch_bounds__(256, 4) void qconv_fused(const float* __restrict__ rho,
                                                      const float* __restrict__ ws,
                                                      float* __restrict__ out) {
    __shared__ float S[8192];  // [32 rows][256 cols] swizzled = 32 KB
    const int t   = threadIdx.x;
    const int bid = blockIdx.x;
    const int bx2 = bid & 3;
    const int by1 = (bid >> 2) & 3;
    const int bx1 = (bid >> 4) & 3;
    const int b   = bid >> 6;

    const float* __restrict__ UX = ws;       // Ufx[8][8] (uniform -> s_load)
    const float* __restrict__ UY = ws + 64;  // Ufy[8][8]

    const size_t B0      = (size_t)b << 20;
    const int    rowbase = bx1 * 256 + by1 * 8;
    const int    cg      = bx2 * 256 + t;

    const float* __restrict__ src = rho + B0 + (size_t)rowbase * 1024 + cg;

    // ---- streaming row transform: acc[i*8+jj] = row (x1m=i, y1m=jj) ----
    float acc[64];
#pragma unroll
    for (int k = 0; k < 8; ++k) {
        float raw[8];
#pragma unroll
        for (int j = 0; j < 8; ++j)
            raw[j] = src[(size_t)(k * 32 + j) * 1024];
        STREAM_GROUP(k, raw, acc, UX, UY)
    }

    // swizzled column slot per row-parity: chunk (t>>2) XOR'd by (r&7)
    int cswz[8];
#pragma unroll
    for (int r7 = 0; r7 < 8; ++r7)
        cswz[r7] = ((((t >> 2) ^ r7) << 2) | (t & 3));

    // ---- half-pass 1: rows 0..31 ----
#pragma unroll
    for (int r = 0; r < 32; ++r) S[r * 256 + cswz[r & 7]] = acc[r];
    __syncthreads();

    const int wid = t >> 6;
    if (wid < 2) {
        // waves 0,1: rr in [0,32), by2 = t>>5 in [0,4)
        col_phase(S, UX, UY, out, B0, rowbase, bx2, t & 31, t >> 5);
    }
    __syncthreads();

    // ---- half-pass 2: rows 32..63 ----
#pragma unroll
    for (int r = 32; r < 64; ++r) S[(r - 32) * 256 + cswz[r & 7]] = acc[r];
    __syncthreads();

    if (wid >= 2) {
        const int u = t - 128;
        col_phase(S, UX, UY, out, B0, rowbase, bx2, 32 + (u & 31), u >> 5);
    }
}

extern "C" void kernel_launch(void* const* d_in, const int* in_sizes, int n_in,
                              void* d_out, int out_size, void* d_ws, size_t ws_size,
                              hipStream_t stream) {
    const float* rho   = (const float*)d_in[0];
    const float* phi_x = (const float*)d_in[1];
    const float* phi_y = (const float*)d_in[2];
    float* out = (float*)d_out;
    float* ws  = (float*)d_ws;

    setup_uf<<<1, 64, 0, stream>>>(phi_x, phi_y, ws);
    qconv_fused<<<1024, 256, 0, stream>>>(rho, ws, out);
}

// Round 6
// 43.120 us; speedup vs baseline: 1.1090x; 1.1090x over previous
//
#include <hip/hip_runtime.h>
#include <math.h>

// QConv2d: new_rho = kron(Ux,Uy) @ rho @ kron(Ux,Uy)^T
// Ux,Uy 32x32 block-diagonal with four IDENTICAL 8x8 orthogonal blocks.
// Four independent length-8 contractions on axes (x1,y1,x2,y2).
//
// Block = (b,bx1,by1,bx2) = 64 rows x 256 contiguous cols, 256 threads.
// STREAMING form: for each x-group k: load 8 rows -> y-contract -> rank-1
// accumulate with UX[:,k]. Transpose via 32KB [32][256] swizzled LDS in two
// half-passes (waves 0,1 consume rows 0..31; waves 2,3 rows 32..63).
// Direct float4 stores (by2 0..3 covered within one phase -> full 128B lines).
//
// NOTE: plain __launch_bounds__(256). The (256,4) variant made the backend
// pin VGPR=64 and spill acc[] to scratch (+30MB WRITE, +11MB FETCH, slower).
// Grid already caps residency at 4 blocks/CU; natural ~110 VGPR keeps
// 4 waves/SIMD with zero spill.

__global__ void setup_uf(const float* __restrict__ phi_x,
                         const float* __restrict__ phi_y,
                         float* __restrict__ ws) {
    const int t = threadIdx.x;
    if (t < 2) {
        const float* phi = (t == 0) ? phi_x : phi_y;
        float U[8][8];
#pragma unroll
        for (int i = 0; i < 8; ++i)
#pragma unroll
            for (int j = 0; j < 8; ++j) U[i][j] = (i == j) ? 1.0f : 0.0f;
        int idx = 0;
#pragma unroll
        for (int i = 1; i < 8; ++i) {
#pragma unroll
            for (int j = i; j >= 1; --j) {
                const float c = cosf(phi[idx]);
                const float s = sinf(phi[idx]);
#pragma unroll
                for (int m = 0; m < 8; ++m) {
                    const float a = U[j - 1][m], b = U[j][m];
                    U[j - 1][m] = c * a + s * b;
                    U[j][m]     = -s * a + c * b;
                }
                ++idx;
            }
        }
        float* o = ws + t * 64;
#pragma unroll
        for (int i = 0; i < 8; ++i)
#pragma unroll
            for (int j = 0; j < 8; ++j) o[i * 8 + j] = U[i][j];
    }
}

// y-contract raw[8] with UY, then accumulate UX[:,k] (x) w[] into acc[64].
#define STREAM_GROUP(K, RAW, ACC, UXP, UYP)                                    \
    {                                                                          \
        float w_[8];                                                           \
        _Pragma("unroll")                                                      \
        for (int jj = 0; jj < 8; ++jj) {                                       \
            float a_ = 0.0f;                                                   \
            _Pragma("unroll")                                                  \
            for (int j = 0; j < 8; ++j)                                        \
                a_ = fmaf((UYP)[jj * 8 + j], (RAW)[j], a_);                    \
            w_[jj] = a_;                                                       \
        }                                                                      \
        _Pragma("unroll")                                                      \
        for (int i = 0; i < 8; ++i) {                                          \
            const float ux_ = (UXP)[i * 8 + (K)];                              \
            _Pragma("unroll")                                                  \
            for (int jj = 0; jj < 8; ++jj) {                                   \
                if ((K) == 0)                                                  \
                    (ACC)[i * 8 + jj] = ux_ * w_[jj];                          \
                else                                                           \
                    (ACC)[i * 8 + jj] =                                        \
                        fmaf(ux_, w_[jj], (ACC)[i * 8 + jj]);                  \
            }                                                                  \
        }                                                                      \
    }

// Column (y2,x2) transform + direct store for one (rr, by2) unit.
// S holds 32 swizzled rows (base row rr & ~31).
__device__ __forceinline__ void col_phase(const float* __restrict__ S,
                                          const float* __restrict__ UX,
                                          const float* __restrict__ UY,
                                          float* __restrict__ out,
                                          size_t B0, int rowbase, int bx2,
                                          int rr, int by2) {
    const int r2 = rr & 31;
    const int r7 = r2 & 7;
    const float* __restrict__ Srow = S + r2 * 256;

    float q[64];
#pragma unroll
    for (int k = 0; k < 8; ++k) {
        const int c0 = (((k * 8 + by2 * 2 + 0) ^ r7) << 2);
        const int c1 = (((k * 8 + by2 * 2 + 1) ^ r7) << 2);
        const float4 q0 = *reinterpret_cast<const float4*>(&Srow[c0]);
        const float4 q1 = *reinterpret_cast<const float4*>(&Srow[c1]);
        float raw[8];
        raw[0] = q0.x; raw[1] = q0.y; raw[2] = q0.z; raw[3] = q0.w;
        raw[4] = q1.x; raw[5] = q1.y; raw[6] = q1.z; raw[7] = q1.w;
        STREAM_GROUP(k, raw, q, UX, UY)
    }

    const int gr = rowbase + ((rr >> 3) * 32) + (rr & 7);
    float* __restrict__ dst = out + B0 + (size_t)gr * 1024 + bx2 * 256 + by2 * 8;
#pragma unroll
    for (int i = 0; i < 8; ++i) {
        *reinterpret_cast<float4*>(dst + i * 32) =
            make_float4(q[i * 8 + 0], q[i * 8 + 1], q[i * 8 + 2], q[i * 8 + 3]);
        *reinterpret_cast<float4*>(dst + i * 32 + 4) =
            make_float4(q[i * 8 + 4], q[i * 8 + 5], q[i * 8 + 6], q[i * 8 + 7]);
    }
}

__global__ __launch_bounds__(256) void qconv_fused(const float* __restrict__ rho,
                                                   const float* __restrict__ ws,
                                                   float* __restrict__ out) {
    __shared__ float S[8192];  // [32 rows][256 cols] swizzled = 32 KB
    const int t   = threadIdx.x;
    const int bid = blockIdx.x;
    const int bx2 = bid & 3;
    const int by1 = (bid >> 2) & 3;
    const int bx1 = (bid >> 4) & 3;
    const int b   = bid >> 6;

    const float* __restrict__ UX = ws;       // Ufx[8][8] (uniform -> s_load)
    const float* __restrict__ UY = ws + 64;  // Ufy[8][8]

    const size_t B0      = (size_t)b << 20;
    const int    rowbase = bx1 * 256 + by1 * 8;
    const int    cg      = bx2 * 256 + t;

    const float* __restrict__ src = rho + B0 + (size_t)rowbase * 1024 + cg;

    // ---- streaming row transform: acc[i*8+jj] = row (x1m=i, y1m=jj) ----
    float acc[64];
#pragma unroll
    for (int k = 0; k < 8; ++k) {
        float raw[8];
#pragma unroll
        for (int j = 0; j < 8; ++j)
            raw[j] = src[(size_t)(k * 32 + j) * 1024];
        STREAM_GROUP(k, raw, acc, UX, UY)
    }

    // swizzled column slot per row-parity: chunk (t>>2) XOR'd by (r&7)
    int cswz[8];
#pragma unroll
    for (int r7 = 0; r7 < 8; ++r7)
        cswz[r7] = ((((t >> 2) ^ r7) << 2) | (t & 3));

    // ---- half-pass 1: rows 0..31 ----
#pragma unroll
    for (int r = 0; r < 32; ++r) S[r * 256 + cswz[r & 7]] = acc[r];
    __syncthreads();

    const int wid = t >> 6;
    if (wid < 2) {
        // waves 0,1: rr in [0,32), by2 = t>>5 in [0,4)
        col_phase(S, UX, UY, out, B0, rowbase, bx2, t & 31, t >> 5);
    }
    __syncthreads();

    // ---- half-pass 2: rows 32..63 ----
#pragma unroll
    for (int r = 32; r < 64; ++r) S[(r - 32) * 256 + cswz[r & 7]] = acc[r];
    __syncthreads();

    if (wid >= 2) {
        const int u = t - 128;
        col_phase(S, UX, UY, out, B0, rowbase, bx2, 32 + (u & 31), u >> 5);
    }
}

extern "C" void kernel_launch(void* const* d_in, const int* in_sizes, int n_in,
                              void* d_out, int out_size, void* d_ws, size_t ws_size,
                              hipStream_t stream) {
    const float* rho   = (const float*)d_in[0];
    const float* phi_x = (const float*)d_in[1];
    const float* phi_y = (const float*)d_in[2];
    float* out = (float*)d_out;
    float* ws  = (float*)d_ws;

    setup_uf<<<1, 64, 0, stream>>>(phi_x, phi_y, ws);
    qconv_fused<<<1024, 256, 0, stream>>>(rho, ws, out);
}